// Round 1
// baseline (173.501 us; speedup 1.0000x reference)
//
#include <hip/hip_runtime.h>

#define NODE 2048
#define KDIM 2048
#define CLUSTER 32
#define IN_DIM 64
#define OUT_DIM 64
#define BATCH 32

typedef short short8 __attribute__((ext_vector_type(8)));
typedef float f32x4 __attribute__((ext_vector_type(4)));

__device__ __forceinline__ short f2bf(float f) {
  unsigned u = __float_as_uint(f);
  u += 0x7fffu + ((u >> 16) & 1u);   // round-to-nearest-even
  return (short)(u >> 16);
}
__device__ __forceinline__ float bf2f(short s) {
  return __uint_as_float(((unsigned)(unsigned short)s) << 16);
}

// ---------------------------------------------------------------------------
// k1: w = alpha @ beta, stored as bf16 in MFMA-B fragment layout
//     w_frag[n][i>>3][o][i&7]  (short8 granule = 8 consecutive i for fixed o)
// grid 1024 x 256 thr: block = (4 nodes) x (half of i) ; thread = (o, i-group)
// ---------------------------------------------------------------------------
__global__ __launch_bounds__(256) void k1_wgen(
    const float* __restrict__ alpha, const float* __restrict__ beta,
    short8* __restrict__ w_frag) {
  const int bid = blockIdx.x;
  const int ngrp = bid >> 1;
  const int ihalf = bid & 1;
  const int t = threadIdx.x;
  const int o = t & 63;
  const int igl = t >> 6;              // 0..3
  const int i0 = ihalf * 32 + igl * 8; // this thread's 8 consecutive i
  const int n0 = ngrp * 4;

  float acc[4][8];
#pragma unroll
  for (int r = 0; r < 4; ++r)
#pragma unroll
    for (int j = 0; j < 8; ++j) acc[r][j] = 0.f;

  for (int k = 0; k < CLUSTER; ++k) {
    float av[4];
#pragma unroll
    for (int r = 0; r < 4; ++r) av[r] = alpha[(n0 + r) * CLUSTER + k];
    const float* bp = beta + k * (IN_DIM * OUT_DIM) + i0 * OUT_DIM + o;
#pragma unroll
    for (int j = 0; j < 8; ++j) {
      float bv = bp[j * OUT_DIM];
#pragma unroll
      for (int r = 0; r < 4; ++r) acc[r][j] += av[r] * bv;
    }
  }
#pragma unroll
  for (int r = 0; r < 4; ++r) {
    short8 s;
#pragma unroll
    for (int j = 0; j < 8; ++j) s[j] = f2bf(acc[r][j]);
    w_frag[((n0 + r) * 8 + (i0 >> 3)) * 64 + o] = s;
  }
}

// ---------------------------------------------------------------------------
// k2: h2[b,n,o] = sum_i h[b,n,i]*w[n,i,o] + bias[o]
// One wave per node n: A = h-slab (M=32 batches x K=64), B = w[n] (64x64).
// Output stored bf16 in fragment layout h2_frag[b][m>>3][o][m&7].
// ---------------------------------------------------------------------------
__global__ __launch_bounds__(64) void k2_h2(
    const float* __restrict__ h, const short8* __restrict__ w_frag,
    const float* __restrict__ bias, short* __restrict__ h2_frag) {
  const int n = blockIdx.x;
  const int l = threadIdx.x;
  const int lr = l & 15, lk = l >> 4;

  // A fragments: lane holds h[row=m*16+lr][n][k = kf*32 + lk*8 + j]
  short8 afr[2][2];
#pragma unroll
  for (int m = 0; m < 2; ++m)
#pragma unroll
    for (int kf = 0; kf < 2; ++kf) {
      const float* hp =
          h + ((size_t)(m * 16 + lr) * NODE + n) * IN_DIM + kf * 32 + lk * 8;
      f32x4 v0 = *(const f32x4*)hp;
      f32x4 v1 = *(const f32x4*)(hp + 4);
      short8 s;
#pragma unroll
      for (int j = 0; j < 4; ++j) { s[j] = f2bf(v0[j]); s[j + 4] = f2bf(v1[j]); }
      afr[m][kf] = s;
    }

  // B fragments straight from fragment-layout w
  short8 bfr[4][2];
#pragma unroll
  for (int ng = 0; ng < 4; ++ng)
#pragma unroll
    for (int kf = 0; kf < 2; ++kf)
      bfr[ng][kf] = w_frag[(n * 8 + kf * 4 + lk) * 64 + ng * 16 + lr];

  f32x4 acc[2][4];
#pragma unroll
  for (int m = 0; m < 2; ++m)
#pragma unroll
    for (int ng = 0; ng < 4; ++ng) acc[m][ng] = (f32x4){0.f, 0.f, 0.f, 0.f};

#pragma unroll
  for (int kf = 0; kf < 2; ++kf)
#pragma unroll
    for (int m = 0; m < 2; ++m)
#pragma unroll
      for (int ng = 0; ng < 4; ++ng)
        acc[m][ng] = __builtin_amdgcn_mfma_f32_16x16x32_bf16(
            afr[m][kf], bfr[ng][kf], acc[m][ng], 0, 0, 0);

#pragma unroll
  for (int m = 0; m < 2; ++m)
#pragma unroll
    for (int ng = 0; ng < 4; ++ng) {
      const int o = ng * 16 + lr;
      const float bv = bias[o];
#pragma unroll
      for (int r = 0; r < 4; ++r) {
        const int b = m * 16 + lk * 4 + r;  // D row = batch
        h2_frag[(((size_t)b * 256 + (n >> 3)) * 64 + o) * 8 + (n & 7)] =
            f2bf(acc[m][ng][r] + bv);
      }
    }
}

// ---------------------------------------------------------------------------
// k3 (hot): out[b] = a[b] @ h2[b] + h2[b]
// 512 blocks x 256 thr (4 waves). BM=128, wave owns 32 rows (2 m-frags x 4
// n-frags). A: direct global f32 -> bf16 convert. B: 16B frag loads from
// h2_frag (L2). Register double-buffered K pipeline, no LDS, no barriers.
// ---------------------------------------------------------------------------
__global__ __launch_bounds__(256) void k3_main(
    const float* __restrict__ a, const short* __restrict__ h2f,
    float* __restrict__ out) {
  const int bid0 = blockIdx.x;                  // 512
  const int swz = (bid0 & 7) * 64 + (bid0 >> 3);  // XCD-cluster same-batch blocks
  const int b = swz >> 4;                       // 32 batches
  const int rt = swz & 15;                      // 16 row tiles
  const int t = threadIdx.x;
  const int wid = t >> 6;
  const int l = t & 63;
  const int lr = l & 15, lk = l >> 4;
  const int rowbase = rt * 128 + wid * 32;

  const float* ap0 = a + (size_t)b * NODE * KDIM + (size_t)lk * 8;
  const float* apm[2];
  apm[0] = ap0 + (size_t)(rowbase + lr) * KDIM;
  apm[1] = ap0 + (size_t)(rowbase + 16 + lr) * KDIM;
  const short8* bbase = (const short8*)h2f + ((size_t)b * 256 + lk) * 64 + lr;

  f32x4 acc[2][4];
#pragma unroll
  for (int m = 0; m < 2; ++m)
#pragma unroll
    for (int ng = 0; ng < 4; ++ng) acc[m][ng] = (f32x4){0.f, 0.f, 0.f, 0.f};

  f32x4 aA[2][2], aB[2][2];
  short8 bA[4], bB[4];

#define LOADK(k0, AR, BR)                                              \
  do {                                                                 \
    _Pragma("unroll") for (int m_ = 0; m_ < 2; ++m_) {                 \
      const float* p_ = apm[m_] + (k0);                                \
      AR[m_][0] = *(const f32x4*)p_;                                   \
      AR[m_][1] = *(const f32x4*)(p_ + 4);                             \
    }                                                                  \
    const short8* q_ = bbase + ((k0) >> 3) * 64;                       \
    _Pragma("unroll") for (int ng_ = 0; ng_ < 4; ++ng_) BR[ng_] = q_[ng_ * 16]; \
  } while (0)

#define MFMASTEP(AR, BR)                                               \
  do {                                                                 \
    short8 afr_[2];                                                    \
    _Pragma("unroll") for (int m_ = 0; m_ < 2; ++m_) {                 \
      short8 s_;                                                       \
      _Pragma("unroll") for (int j_ = 0; j_ < 4; ++j_) {               \
        s_[j_] = f2bf(AR[m_][0][j_]);                                  \
        s_[j_ + 4] = f2bf(AR[m_][1][j_]);                              \
      }                                                                \
      afr_[m_] = s_;                                                   \
    }                                                                  \
    _Pragma("unroll") for (int ng_ = 0; ng_ < 4; ++ng_)                \
      _Pragma("unroll") for (int m_ = 0; m_ < 2; ++m_)                 \
        acc[m_][ng_] = __builtin_amdgcn_mfma_f32_16x16x32_bf16(        \
            afr_[m_], BR[ng_], acc[m_][ng_], 0, 0, 0);                 \
  } while (0)

  LOADK(0, aA, bA);
#pragma unroll 1
  for (int k0 = 0; k0 < KDIM; k0 += 64) {
    LOADK(k0 + 32, aB, bB);
    MFMASTEP(aA, bA);
    if (k0 + 64 < KDIM) LOADK(k0 + 64, aA, bA);
    MFMASTEP(aB, bB);
  }
#undef LOADK
#undef MFMASTEP

  // epilogue: residual (+h2) fused, from bf16 fragment buffer (L2-hot)
#pragma unroll
  for (int m = 0; m < 2; ++m)
#pragma unroll
    for (int ng = 0; ng < 4; ++ng) {
      const int col = ng * 16 + lr;
#pragma unroll
      for (int r = 0; r < 4; ++r) {
        const int row = rowbase + m * 16 + lk * 4 + r;
        float resid =
            bf2f(h2f[(((size_t)b * 256 + (row >> 3)) * 64 + col) * 8 + (row & 7)]);
        out[((size_t)b * NODE + row) * 64 + col] = acc[m][ng][r] + resid;
      }
    }
}

extern "C" void kernel_launch(void* const* d_in, const int* in_sizes, int n_in,
                              void* d_out, int out_size, void* d_ws, size_t ws_size,
                              hipStream_t stream) {
  const float* a     = (const float*)d_in[0];
  const float* h     = (const float*)d_in[1];
  const float* alpha = (const float*)d_in[2];
  const float* beta  = (const float*)d_in[3];
  const float* bias  = (const float*)d_in[4];
  float* out = (float*)d_out;

  // workspace: w_frag bf16 16 MiB @ 0, h2_frag bf16 8 MiB @ 16 MiB
  short8* w_frag = (short8*)d_ws;
  short*  h2_frag = (short*)((char*)d_ws + (size_t)(16u << 20));

  k1_wgen<<<dim3(1024), dim3(256), 0, stream>>>(alpha, beta, w_frag);
  k2_h2 <<<dim3(NODE), dim3(64),  0, stream>>>(h, w_frag, bias, h2_frag);
  k3_main<<<dim3(512), dim3(256), 0, stream>>>(a, h2_frag, out);
}